// Round 1
// 590.315 us; speedup vs baseline: 1.5460x; 1.5460x over previous
//
#include <hip/hip_runtime.h>

// DirectionalFilterBank: 3-level binary tree of (shear ±1 -> depthwise 9x9 conv).
// shear(x,s)[h,w] = 0.5*(x[h,c0]+x[h,c0+1]), c0 = w + s*h + (s>0 ? -128 : 127),
// defined on w in [0,256); conv zero-pads the SHEARED image by 4 on all sides.
// Filter is rank-2 separable: filt_c = -(A (x) A) + (B (x) B) [+ center delta, c==0].
//
// R3 geometry (68 us/conv): 256 thr, TH=32, TW=256, serial-14 schedule (keeps 64MB
// producer->consumer pairs L3-resident; batching thrashed L3, R8).
//
// THIS ROUND: kernel is VALU-bound (~2300 instr/thread * 2cyc * 32 waves/CU ~= 60us,
// matching 65us measured); ~45% of that was the scalar staging loop (k/264 division,
// per-element bounds, scalar loads/ds_writes). Rewritten: each WAVE stages one row
// (row index, bounds check, and shear offset g = off+sign*hr are wave-uniform);
// lane L produces sheared cols 4L..4L+3 from x[g+4L..g+4L+4] via one unaligned-f4
// load + one scalar load + 4 FMA + one aligned ds_write_b128. <=1 divergent lane
// per row (span boundary). Halo cols (always zero) zeroed once by 80 threads.
// Staging ~1000 -> ~250 instr/thread. Compute phase and schedule untouched.

#define B_ 4
#define C_ 64
#define H_ 256
#define W_ 256
#define TH 32                 // output rows per block
#define SROWS (TH + 8)        // 40 staged sheared rows
#define SCOLS (W_ + 8)        // 264 staged cols; LDS = 41.25 KiB
#define NPB 2048              // blocks per conv = 4*64*8

// 4-byte-aligned float4 view: shear offset makes global f4 loads dword- but not
// 16B-aligned. Compiler emits a legal unaligned dwordx4 (or split) load.
struct alignas(4) f4u { float x, y, z, w; };

__global__ __launch_bounds__(256) void shear_sepconv_kernel(
    const float* __restrict__ in, float* __restrict__ dst,
    const float* __restrict__ filt, int parity)
{
    __shared__ float s_sh[SROWS][SCOLS];

    const int tid  = threadIdx.x;
    const int bid  = (int)blockIdx.x;
    const int tile = bid & 7;            // H/TH = 8
    const int c    = (bid >> 3) & 63;    // C = 64
    const int b    = bid >> 9;
    const int h0   = tile * TH;
    const int sign = parity ? -1 : 1;
    const int off  = parity ? 127 : -128;

    const float* base = in + ((size_t)b * C_ + c) * (size_t)(H_ * W_);

    // ---- stage sheared rows h0-4 .. h0+35 ----
    // Wave w stages rows r = w + 4u, u = 0..9. Lane L covers sheared cols
    // w' = 4L..4L+3 (stored at j = 4+4L). Needs x[c0..c0+4], c0 = g + 4L,
    // g = off + sign*hr (wave-uniform). Out-of-[0,256) components are zero.
    {
        const int wave = tid >> 6;
        const int lane = tid & 63;

        // halo cols j in [0,4) and [260,264) are always zero: 40 rows x 2 f4s
        if (tid < 80) {
            const int r = tid >> 1;
            *(float4*)&s_sh[r][(tid & 1) ? 260 : 0] = make_float4(0.f, 0.f, 0.f, 0.f);
        }

        #pragma unroll
        for (int u = 0; u < 10; ++u) {
            const int r  = wave + u * 4;
            const int hr = h0 + r - 4;
            float4 v = make_float4(0.f, 0.f, 0.f, 0.f);
            if ((unsigned)hr < 256u) {                       // wave-uniform
                const float* row = base + (size_t)hr * W_;
                const int c0 = off + sign * hr + lane * 4;
                if (c0 >= 0 && c0 <= 251) {                  // fast: fully interior
                    const f4u  a = *(const f4u*)(row + c0);
                    const float e = row[c0 + 4];
                    v.x = 0.5f * (a.x + a.y);
                    v.y = 0.5f * (a.y + a.z);
                    v.z = 0.5f * (a.z + a.w);
                    v.w = 0.5f * (a.w + e);
                } else if (c0 >= -4 && c0 < 256) {           // <=1 lane per row
                    float t0 = ((unsigned)(c0    ) < 256u) ? row[c0    ] : 0.f;
                    float t1 = ((unsigned)(c0 + 1) < 256u) ? row[c0 + 1] : 0.f;
                    float t2 = ((unsigned)(c0 + 2) < 256u) ? row[c0 + 2] : 0.f;
                    float t3 = ((unsigned)(c0 + 3) < 256u) ? row[c0 + 3] : 0.f;
                    float t4 = ((unsigned)(c0 + 4) < 256u) ? row[c0 + 4] : 0.f;
                    v.x = 0.5f * (t0 + t1);
                    v.y = 0.5f * (t1 + t2);
                    v.z = 0.5f * (t2 + t3);
                    v.w = 0.5f * (t3 + t4);
                }
                // else: fully outside -> zero
            }
            *(float4*)&s_sh[r][4 + lane * 4] = v;            // 16B-aligned
        }
    }

    // ---- separable factors from channel 1 (uniform; identical for all c) ----
    const float* f1 = filt + 81;
    const float A4  = sqrtf(fmaxf(-f1[4 * 9 + 4], 0.f));
    const float rA4 = 1.f / A4;
    const float A0  = -f1[0 * 9 + 4] * rA4;
    const float A2  = -f1[2 * 9 + 4] * rA4;
    const float A6  = -f1[6 * 9 + 4] * rA4;
    const float A8  = -f1[8 * 9 + 4] * rA4;
    const float B5  = sqrtf(fmaxf(f1[5 * 9 + 5], 0.f));
    const float rB5 = 1.f / B5;
    const float B1  = f1[1 * 9 + 5] * rB5;
    const float B3  = f1[3 * 9 + 5] * rB5;
    const float B7  = f1[7 * 9 + 5] * rB5;
    const float vc[9] = {-A0, B1, -A2, B3, -A4, B5, -A6, B7, -A8};

    __syncthreads();

    // ---- compute: 4 row-groups x 8 rows; thread = 4 cols x 8 rows (window 16) ----
    const int rg   = tid >> 6;           // 0..3 -> out rows rg*8 .. rg*8+7
    const int lane = tid & 63;
    const int w0   = lane * 4;

    float acc[8][4];
    #pragma unroll
    for (int i = 0; i < 8; ++i)
        #pragma unroll
        for (int j = 0; j < 4; ++j) acc[i][j] = 0.f;

    #pragma unroll
    for (int t = 0; t < 16; ++t) {       // staged rows rg*8 + t
        const int rr = rg * 8 + t;
        const float4 sa = *(const float4*)&s_sh[rr][w0];
        const float4 sb = *(const float4*)&s_sh[rr][w0 + 4];
        const float4 sc4 = *(const float4*)&s_sh[rr][w0 + 8];
        const float s[12] = {sa.x, sa.y, sa.z, sa.w,
                             sb.x, sb.y, sb.z, sb.w,
                             sc4.x, sc4.y, sc4.z, sc4.w};
        float ha[4], hb[4];
        #pragma unroll
        for (int j = 0; j < 4; ++j) {
            ha[j] = fmaf(A8, s[j + 8],
                    fmaf(A6, s[j + 6],
                    fmaf(A4, s[j + 4],
                    fmaf(A2, s[j + 2], A0 * s[j]))));
            hb[j] = fmaf(B7, s[j + 7],
                    fmaf(B5, s[j + 5],
                    fmaf(B3, s[j + 3], B1 * s[j + 1])));
        }
        #pragma unroll
        for (int i = 0; i < 8; ++i) {
            const int ky = t - i;        // compile-time after unroll
            if (ky >= 0 && ky < 9) {
                #pragma unroll
                for (int j = 0; j < 4; ++j) {
                    const float hv = (ky & 1) ? hb[j] : ha[j];
                    acc[i][j] = fmaf(vc[ky], hv, acc[i][j]);
                }
            }
        }
    }

    // channel-0 delta: += sheared image value at the output location
    if (c == 0) {
        #pragma unroll
        for (int i = 0; i < 8; ++i) {
            const float4 sv = *(const float4*)&s_sh[rg * 8 + i + 4][w0 + 4];
            acc[i][0] += sv.x; acc[i][1] += sv.y; acc[i][2] += sv.z; acc[i][3] += sv.w;
        }
    }

    float* optr = dst + (((size_t)b * C_ + c) * H_ + h0 + rg * 8) * (size_t)W_ + w0;
    #pragma unroll
    for (int i = 0; i < 8; ++i) {
        const float4 v = {acc[i][0], acc[i][1], acc[i][2], acc[i][3]};
        *(float4*)(optr + (size_t)i * W_) = v;
    }
}

extern "C" void kernel_launch(void* const* d_in, const int* in_sizes, int n_in,
                              void* d_out, int out_size, void* d_ws, size_t ws_size,
                              hipStream_t stream) {
    const float* x    = (const float*)d_in[0];
    const float* filt = (const float*)d_in[1];
    float* out = (float*)d_out;
    float* wsb = (float*)d_ws;          // one 64 MiB spare tensor
    const size_t N = (size_t)B_ * C_ * H_ * W_;

    float* S[8];
    for (int k = 0; k < 8; ++k) S[k] = out + (size_t)k * N;

    const dim3 grid(NPB);
    const dim3 block(256);

    auto launch = [&](const float* src, float* dst, int parity) {
        shear_sepconv_kernel<<<grid, block, 0, stream>>>(src, dst, filt, parity);
    };

    // Serial tree schedule (DFS) — keeps each 64MB producer->consumer pair L3-resident.
    launch(x,    wsb,  0);   // A
    launch(wsb,  S[7], 0);   // AA (S7 temp)
    launch(S[7], S[0], 0);   // out0
    launch(S[7], S[1], 1);   // out1
    launch(wsb,  S[7], 1);   // AB
    launch(S[7], S[2], 0);   // out2
    launch(S[7], S[3], 1);   // out3
    launch(x,    S[7], 1);   // B
    launch(S[7], wsb,  0);   // BA
    launch(wsb,  S[4], 0);   // out4
    launch(wsb,  S[5], 1);   // out5
    launch(S[7], wsb,  1);   // BB
    launch(wsb,  S[6], 0);   // out6
    launch(wsb,  S[7], 1);   // out7
}